// Round 7
// baseline (75.673 us; speedup 1.0000x reference)
//
#include <hip/hip_runtime.h>
#include <math.h>

// ThrusterLag: y[k] = a*y[k-1] + (1-a)*tanh(2*deadzone((u-7.5)/2.5)), y[-1]=u_nl[0]
// a = exp(-DT/tau), tau = softplus(tau_param) + TAU_MIN, per channel (C=8).
// Shapes: u_seq (512, 8192, 8) f32; out same. Traffic floor: 268 MB.
//
// Single-pass: one block per row, 512 threads (8 waves), 8 tiles of 1024 steps.
// Thread t owns 2 steps x 8 ch (64B contiguous). Zero-seeded local scan in
// registers; intra-wave carry via 6-round shuffle scan (multiplier squares
// a^2 -> a^128); cross-wave carry via LDS Horner over 8 wave totals.
// y_i = l_i + a^{i+1} * C. All tile-invariant decay powers (M=a^128, Mw=M^w,
// M8=a^1024, D=a^(2*lane)) precomputed closed-form at init. Channel math on
// v4f ext-vectors so the compiler can emit packed v_pk_*_f32.
// R5 lesson: keep VGPR<=128, launch_bounds(512,2), no forced spills.

typedef float v4f __attribute__((ext_vector_type(4)));

constexpr int kB    = 512;
constexpr int kL    = 8192;
constexpr int kC    = 8;
constexpr int kT    = 512;            // threads per block (8 waves)
constexpr int kSEG  = 2;              // steps per thread per tile
constexpr int kTile = kT * kSEG;      // 1024 steps per tile
constexpr int kNT   = kL / kTile;     // 8 tiles per row

constexpr float kDT     = 0.01f;
constexpr float kTauMin = 0.01f;

__device__ __forceinline__ float softplus_f(float p) {
    return fmaxf(p, 0.0f) + log1pf(__expf(-fabsf(p)));
}

// tanh(2*u_dz) = (e^{4*u_dz}-1)/(e^{4*u_dz}+1); 4*u_dz folded:
// s = 4*(u-7.5)/2.5 = 1.6u-12; 4*u_dz = copysign(max(|s|-0.2,0), s)
__device__ __forceinline__ float u_nl(float u) {
    float s = fmaf(u, 1.6f, -12.0f);
    float m = fmaxf(fabsf(s) - 0.2f, 0.0f);
    float e = __expf(copysignf(m, s));          // s in [-4,4]: no overflow
    return (e - 1.0f) * __builtin_amdgcn_rcpf(e + 1.0f);
}

__global__ __launch_bounds__(kT, 2) void scan_row(const float* __restrict__ u,
                                                  const float* __restrict__ tp,
                                                  float* __restrict__ out) {
    const int row  = blockIdx.x;
    const int t    = threadIdx.x;
    const int lane = t & 63;
    const int w    = t >> 6;          // wave id 0..7

    // ---- per-channel constants (v4f pairs; index [c>>2][c&3]) ----
    v4f a[2], om[2], D[2], Mw[2], M8[2], R[2];
    #pragma unroll
    for (int c = 0; c < kC; ++c) {
        float tau = softplus_f(tp[c]) + kTauMin;
        float lna = -kDT / tau;                              // ln(a) < 0
        a[c >> 2][c & 3]  = __expf(lna);
        om[c >> 2][c & 3] = 1.0f - __expf(lna);
        D[c >> 2][c & 3]  = __expf(lna * (float)(kSEG * lane));      // a^(2*lane)
        Mw[c >> 2][c & 3] = __expf(lna * (float)(kSEG * 64 * w));    // (a^128)^w
        M8[c >> 2][c & 3] = __expf(lna * (float)kTile);              // a^1024
    }

    const float* base  = u   + (size_t)row * kL * kC;
    float*       obase = out + (size_t)row * kL * kC;

    // row carry R = y[-1] = u_nl(u[row, 0, :]) (uniform broadcast load)
    {
        v4f q0 = *(const v4f*)(base);
        v4f q1 = *(const v4f*)(base + 4);
        R[0] = (v4f){u_nl(q0.x), u_nl(q0.y), u_nl(q0.z), u_nl(q0.w)};
        R[1] = (v4f){u_nl(q1.x), u_nl(q1.y), u_nl(q1.z), u_nl(q1.w)};
    }

    __shared__ v4f Tl[2][8][2];        // [slot][wave][half] wave totals

    // prefetch tile 0 (thread's 64B)
    const float* tb = base + (size_t)t * kSEG * kC;
    v4f x0 = *(const v4f*)(tb);
    v4f x1 = *(const v4f*)(tb + 4);
    v4f x2 = *(const v4f*)(tb + 8);
    v4f x3 = *(const v4f*)(tb + 12);

    for (int tile = 0; tile < kNT; ++tile) {
        const int s = tile & 1;

        // ---- local zero-seeded scan (2 steps, packed channel math) ----
        v4f n0 = (v4f){u_nl(x0.x), u_nl(x0.y), u_nl(x0.z), u_nl(x0.w)};
        v4f n1 = (v4f){u_nl(x1.x), u_nl(x1.y), u_nl(x1.z), u_nl(x1.w)};
        v4f n2 = (v4f){u_nl(x2.x), u_nl(x2.y), u_nl(x2.z), u_nl(x2.w)};
        v4f n3 = (v4f){u_nl(x3.x), u_nl(x3.y), u_nl(x3.z), u_nl(x3.w)};
        v4f l00 = om[0] * n0;
        v4f l01 = om[1] * n1;
        v4f l10 = a[0] * l00 + om[0] * n2;
        v4f l11 = a[1] * l01 + om[1] * n3;

        // ---- issue next tile's loads (hide HBM under scan phase) ----
        if (tile + 1 < kNT) {
            const float* nb = base + ((size_t)(tile + 1) * kTile + (size_t)t * kSEG) * kC;
            x0 = *(const v4f*)(nb);
            x1 = *(const v4f*)(nb + 4);
            x2 = *(const v4f*)(nb + 8);
            x3 = *(const v4f*)(nb + 12);
        }

        // ---- intra-wave inclusive shuffle scan (multiplier squares) ----
        v4f I0 = l10, I1 = l11;
        v4f Ms0 = a[0] * a[0], Ms1 = a[1] * a[1];   // a^2
        #pragma unroll
        for (int d = 1; d < 64; d <<= 1) {
            const bool en = lane >= d;
            #pragma unroll
            for (int cc = 0; cc < 4; ++cc) {
                float u0 = __shfl_up(I0[cc], (unsigned)d, 64);
                float u1 = __shfl_up(I1[cc], (unsigned)d, 64);
                u0 = en ? u0 : 0.0f;
                u1 = en ? u1 : 0.0f;
                I0[cc] += Ms0[cc] * u0;
                I1[cc] += Ms1[cc] * u1;
            }
            Ms0 *= Ms0;
            Ms1 *= Ms1;
        }
        // Ms now = a^128 = M (cross-wave step decay)

        // ---- publish wave totals (vector LDS writes) ----
        if (lane == 63) {
            Tl[s][w][0] = I0;
            Tl[s][w][1] = I1;
        }
        __syncthreads();

        // same-wave exclusive carry
        v4f E0, E1;
        #pragma unroll
        for (int cc = 0; cc < 4; ++cc) {
            float e0 = __shfl_up(I0[cc], 1u, 64);
            float e1 = __shfl_up(I1[cc], 1u, 64);
            E0[cc] = lane ? e0 : 0.0f;
            E1[cc] = lane ? e1 : 0.0f;
        }

        // cross-wave Horner over 8 wave totals; wave-uniform snapshot at j==w-1
        v4f acc0 = (v4f){0,0,0,0}, acc1 = (v4f){0,0,0,0};
        v4f P0   = (v4f){0,0,0,0}, P1   = (v4f){0,0,0,0};
        #pragma unroll
        for (int j = 0; j < 8; ++j) {
            v4f T0 = Tl[s][j][0];
            v4f T1 = Tl[s][j][1];
            acc0 = Ms0 * acc0 + T0;
            acc1 = Ms1 * acc1 + T1;
            if (j == w - 1) { P0 = acc0; P1 = acc1; }   // wave-uniform branch
        }

        // ---- carry into this thread, row-carry advance, emit ----
        v4f C0 = E0 + D[0] * (P0 + Mw[0] * R[0]);
        v4f C1 = E1 + D[1] * (P1 + Mw[1] * R[1]);
        R[0] = acc0 + M8[0] * R[0];
        R[1] = acc1 + M8[1] * R[1];

        v4f cy0 = a[0] * C0, cy1 = a[1] * C1;
        float* ob = obase + ((size_t)tile * kTile + (size_t)t * kSEG) * kC;
        *(v4f*)(ob)      = l00 + cy0;
        *(v4f*)(ob + 4)  = l01 + cy1;
        *(v4f*)(ob + 8)  = l10 + a[0] * cy0;
        *(v4f*)(ob + 12) = l11 + a[1] * cy1;
    }
}

extern "C" void kernel_launch(void* const* d_in, const int* in_sizes, int n_in,
                              void* d_out, int out_size, void* d_ws, size_t ws_size,
                              hipStream_t stream) {
    const float* u  = (const float*)d_in[0];
    const float* tp = (const float*)d_in[1];
    float* out = (float*)d_out;

    scan_row<<<kB, kT, 0, stream>>>(u, tp, out);
}